// Round 5
// baseline (263.227 us; speedup 1.0000x reference)
//
#include <hip/hip_runtime.h>
#include <hip/hip_bf16.h>
#include <cstddef>
#include <cstdint>

// SwitchFFN: B=2,S=2048,D=512,E=8,H=2048. T=4096 tokens.
// Round 5: wave-parallel router (10-shuffle reduce + lane-parallel softmax),
// cvt_x folded into route_k. GEMMs unchanged from round 4 (passed, 260us).
//   route(+xb cvt) -> bucket -> prefix -> cvt(W1^T,W2^T) ->
//   mfma GEMM1 (gathered A, relu, compact bf16 h) ->
//   mfma GEMM2 (contiguous A, scatter f32 out * rv) -> loss

namespace {

constexpr int T = 4096;
constexpr int D = 512;
constexpr int E = 8;
constexpr int H = 2048;

typedef __attribute__((ext_vector_type(8))) short short8;
typedef __attribute__((ext_vector_type(4))) float f32x4;

struct WS {
  int   counts[8];
  int   cursor[8];
  int   base[8];
  float pi8[8];
  float rv[T];
  int   ridx[T];
  int   list[E * T];
};

constexpr size_t HDR     = (sizeof(WS) + 255) & ~size_t(255);
constexpr size_t XB_OFF  = HDR;                                      // bf16 x   [T][D]
constexpr size_t WT1_OFF = XB_OFF  + 2 * (size_t)T * D;              // bf16 W1^T [E][H][D]
constexpr size_t WT2_OFF = WT1_OFF + 2 * (size_t)E * H * D;          // bf16 W2^T [E][D][H]
constexpr size_t HB_OFF  = WT2_OFF + 2 * (size_t)E * D * H;          // bf16 h (compact) [T][H]

#define GLD16(g, l)                                                       \
  __builtin_amdgcn_global_load_lds(                                       \
      (const __attribute__((address_space(1))) void*)(g),                 \
      (__attribute__((address_space(3))) void*)(l), 16, 0, 0)

__global__ void init_k(WS* ws) {
  int i = threadIdx.x;
  if (i < 8) { ws->counts[i] = 0; ws->cursor[i] = 0; }
}

// One wave per token. Lane reads x[t][lane*8..+7] (coalesced), emits bf16 xb,
// computes 8 expert logits with a halving butterfly (10 shuffles), then a
// lane-parallel 8-wide softmax + 64-bit-key argmax (first-max semantics).
__global__ __launch_bounds__(256) void route_k(const float* __restrict__ x,
                                               const float* __restrict__ Wg,
                                               const float* __restrict__ bg,
                                               __hip_bfloat16* __restrict__ xb,
                                               WS* __restrict__ ws) {
  const int wave = threadIdx.x >> 6;
  const int lane = threadIdx.x & 63;
  const int t = blockIdx.x * 4 + wave;
  const float* xr = x + (size_t)t * D;

  // ---- load 8 consecutive x values, emit bf16 ----
  const float4* xp = reinterpret_cast<const float4*>(xr) + lane * 2;
  float4 a = xp[0], b4 = xp[1];
  float xs[8] = {a.x, a.y, a.z, a.w, b4.x, b4.y, b4.z, b4.w};
  alignas(16) __hip_bfloat16 o[8];
#pragma unroll
  for (int j = 0; j < 8; ++j) o[j] = __float2bfloat16(xs[j]);
  *reinterpret_cast<int4*>(xb + (size_t)t * D + lane * 8) = *reinterpret_cast<int4*>(o);

  // ---- partial logits: lane covers k = lane*8..lane*8+7, all 8 experts ----
  float acc[8] = {0.f, 0.f, 0.f, 0.f, 0.f, 0.f, 0.f, 0.f};
#pragma unroll
  for (int i = 0; i < 8; ++i) {
    const int k = lane * 8 + i;
    const float4* w = reinterpret_cast<const float4*>(Wg + (size_t)k * 8);
    float4 w0 = w[0], w1 = w[1];
    float xv = xs[i];
    acc[0] += xv * w0.x; acc[1] += xv * w0.y; acc[2] += xv * w0.z; acc[3] += xv * w0.w;
    acc[4] += xv * w1.x; acc[5] += xv * w1.y; acc[6] += xv * w1.z; acc[7] += xv * w1.w;
  }

  // ---- halving butterfly: 4+2+1 shuffles -> lane holds expert e(lane) ----
#pragma unroll
  for (int j = 0; j < 4; ++j) {
    float send = (lane & 1) ? acc[j] : acc[j + 4];
    float recv = __shfl_xor(send, 1, 64);
    acc[j] = ((lane & 1) ? acc[j + 4] : acc[j]) + recv;
  }
#pragma unroll
  for (int j = 0; j < 2; ++j) {
    float send = (lane & 2) ? acc[j] : acc[j + 2];
    float recv = __shfl_xor(send, 2, 64);
    acc[j] = ((lane & 2) ? acc[j + 2] : acc[j]) + recv;
  }
  {
    float send = (lane & 4) ? acc[0] : acc[1];
    float recv = __shfl_xor(send, 4, 64);
    acc[0] = ((lane & 4) ? acc[1] : acc[0]) + recv;
  }
  float v = acc[0];
  v += __shfl_xor(v, 8, 64);
  v += __shfl_xor(v, 16, 64);
  v += __shfl_xor(v, 32, 64);
  // expert owned by this lane (bit-reversed low-3 bits)
  const int e = 4 * (lane & 1) + 2 * ((lane >> 1) & 1) + ((lane >> 2) & 1);

  // ---- lane-parallel softmax over the 8-lane group ----
  float lg = v + bg[e];
  float m = lg;
  m = fmaxf(m, __shfl_xor(m, 1, 64));
  m = fmaxf(m, __shfl_xor(m, 2, 64));
  m = fmaxf(m, __shfl_xor(m, 4, 64));
  float p = expf(lg - m);
  float s = p;
  s += __shfl_xor(s, 1, 64);
  s += __shfl_xor(s, 2, 64);
  s += __shfl_xor(s, 4, 64);
  float pr = p / s;
  float psum = pr;
  psum += __shfl_xor(psum, 1, 64);
  psum += __shfl_xor(psum, 2, 64);
  psum += __shfl_xor(psum, 4, 64);
  // argmax with first-max (smallest e wins ties): key = bits(pr)<<8 | (7-e)
  unsigned long long key =
      ((unsigned long long)__float_as_uint(pr) << 8) | (unsigned)(7 - e);
  unsigned long long k2;
  k2 = __shfl_xor(key, 1, 64); key = key > k2 ? key : k2;
  k2 = __shfl_xor(key, 2, 64); key = key > k2 ? key : k2;
  k2 = __shfl_xor(key, 4, 64); key = key > k2 ? key : k2;

  if (lane == 0) {
    int ebest = 7 - (int)(key & 0xffull);
    float prmax = __uint_as_float((unsigned)(key >> 8));
    ws->rv[t] = prmax;
    ws->ridx[t] = ebest;
    atomicAdd(&ws->counts[ebest], 1);
    if (t < 8) ws->pi8[t] = psum * 0.125f;
  }
}

__global__ void build_k(WS* __restrict__ ws) {
  int t = blockIdx.x * 256 + threadIdx.x;
  if (t >= T) return;
  int e = ws->ridx[t];
  int pos = atomicAdd(&ws->cursor[e], 1);
  ws->list[e * T + pos] = t;
}

__global__ void prefix_k(WS* __restrict__ ws) {
  if (threadIdx.x == 0) {
    int b = 0;
#pragma unroll
    for (int e = 0; e < 8; ++e) { ws->base[e] = b; b += ws->counts[e]; }
  }
}

// in [E][K][N] f32 -> out [E][N][K] bf16 (64x64 LDS-tiled transpose+convert)
template <int K, int N>
__global__ __launch_bounds__(256) void cvt_t(const float* __restrict__ in,
                                             __hip_bfloat16* __restrict__ outp) {
  const int e = blockIdx.z;
  in   += (size_t)e * K * N;
  outp += (size_t)e * K * N;
  const int k0 = blockIdx.y * 64, n0 = blockIdx.x * 64;
  __shared__ __hip_bfloat16 tile[64][72];
  const int r = threadIdx.x >> 4, c = (threadIdx.x & 15) * 4;
#pragma unroll
  for (int rr = 0; rr < 4; ++rr) {
    float4 v = *reinterpret_cast<const float4*>(in + (size_t)(k0 + r + rr * 16) * N + n0 + c);
    tile[r + rr * 16][c + 0] = __float2bfloat16(v.x);
    tile[r + rr * 16][c + 1] = __float2bfloat16(v.y);
    tile[r + rr * 16][c + 2] = __float2bfloat16(v.z);
    tile[r + rr * 16][c + 3] = __float2bfloat16(v.w);
  }
  __syncthreads();
  const int n = threadIdx.x >> 2, ch = threadIdx.x & 3;
  alignas(16) __hip_bfloat16 o[16];
#pragma unroll
  for (int i = 0; i < 16; ++i) o[i] = tile[ch * 16 + i][n];
  __hip_bfloat16* dst = outp + (size_t)(n0 + n) * K + k0 + ch * 16;
  reinterpret_cast<int4*>(dst)[0] = reinterpret_cast<int4*>(o)[0];
  reinterpret_cast<int4*>(dst)[1] = reinterpret_cast<int4*>(o)[1];
}

// MFMA GEMM. BM=128, BK=64. A rows gathered (GEMM1) or compact (GEMM2).
// LDS tiles [rows][64] bf16 (128B rows, 8x16B chunks) with XOR chunk swizzle:
// chunk c of row r holds source chunk (c ^ (r&7)); reader applies same XOR.
template <int K, int BN, int WR, int WC, bool SECOND>
__global__ __launch_bounds__(256) void mgemm(const __hip_bfloat16* __restrict__ Ag,
                                             const __hip_bfloat16* __restrict__ Wt,
                                             const float* __restrict__ bias,
                                             __hip_bfloat16* __restrict__ hb,
                                             float* __restrict__ outp,
                                             WS* __restrict__ ws) {
  constexpr int BM = 128;
  constexpr int BK = 64;
  constexpr int NDIM = SECOND ? D : H;      // full N of this GEMM
  constexpr int MS = BM / WR, NS = BN / WC; // per-wave output span
  constexpr int MF = MS / 16, NF = NS / 16;
  constexpr int ACALLS = BM / 32;           // 4KB per global_load_lds round
  constexpr int BCALLS = BN / 32;

  const int e = blockIdx.z;
  const int cnt = ws->counts[e];
  const int m0 = blockIdx.y * BM;
  if (m0 >= cnt) return;
  const int n0 = blockIdx.x * BN;
  const int bas = ws->base[e];
  const int* lst = ws->list + e * T;

  const int tid = threadIdx.x, lane = tid & 63, wave = tid >> 6;
  const int wr = wave / WC, wc = wave % WC;
  const int wrow = wr * MS, wcol = wc * NS;

  __shared__ unsigned char As[BM * 128];
  __shared__ unsigned char Bs[BN * 128];

  // staging source pointers (per thread, per 4KB call); row clamp for tails
  const int srow = tid >> 3;
  const int sj = tid & 7;
  const unsigned short* aptr[ACALLS];
#pragma unroll
  for (int q = 0; q < ACALLS; ++q) {
    int row = q * 32 + srow;
    int jj = sj ^ (row & 7);
    int mrow = m0 + row; if (mrow > cnt - 1) mrow = cnt - 1;
    int arow = SECOND ? (bas + mrow) : lst[mrow];
    aptr[q] = reinterpret_cast<const unsigned short*>(Ag) + (size_t)arow * K + jj * 8;
  }
  const unsigned short* bptr[BCALLS];
#pragma unroll
  for (int q = 0; q < BCALLS; ++q) {
    int row = q * 32 + srow;
    int jj = sj ^ (row & 7);
    bptr[q] = reinterpret_cast<const unsigned short*>(Wt) +
              ((size_t)e * NDIM + n0 + row) * K + jj * 8;
  }

  f32x4 acc[MF][NF] = {};

  for (int k0 = 0; k0 < K; k0 += BK) {
#pragma unroll
    for (int q = 0; q < ACALLS; ++q) GLD16(aptr[q] + k0, As + q * 4096 + (wave << 10));
#pragma unroll
    for (int q = 0; q < BCALLS; ++q) GLD16(bptr[q] + k0, Bs + q * 4096 + (wave << 10));
    __syncthreads();  // compiler drains vmcnt before barrier
#pragma unroll
    for (int s = 0; s < 2; ++s) {
      const int jA = s * 4 + (lane >> 4);
      short8 af[MF], bfr[NF];
#pragma unroll
      for (int m = 0; m < MF; ++m) {
        int row = wrow + m * 16 + (lane & 15);
        af[m] = *reinterpret_cast<const short8*>(As + row * 128 + ((jA ^ (row & 7)) << 4));
      }
#pragma unroll
      for (int n = 0; n < NF; ++n) {
        int row = wcol + n * 16 + (lane & 15);
        bfr[n] = *reinterpret_cast<const short8*>(Bs + row * 128 + ((jA ^ (row & 7)) << 4));
      }
#pragma unroll
      for (int m = 0; m < MF; ++m)
#pragma unroll
        for (int n = 0; n < NF; ++n)
          acc[m][n] = __builtin_amdgcn_mfma_f32_16x16x32_bf16(af[m], bfr[n], acc[m][n], 0, 0, 0);
    }
    __syncthreads();  // reads done before next stage overwrites
  }

  // epilogue — C/D map: col = lane&15, row = (lane>>4)*4 + i
  const int colbase = n0 + wcol + (lane & 15);
  float bia[NF];
#pragma unroll
  for (int n = 0; n < NF; ++n) bia[n] = bias[(size_t)e * NDIM + colbase + n * 16];
#pragma unroll
  for (int m = 0; m < MF; ++m) {
    const int rloc = wrow + m * 16 + ((lane >> 4) << 2);
#pragma unroll
    for (int i = 0; i < 4; ++i) {
      const int r = m0 + rloc + i;
      if (r < cnt) {
        if (!SECOND) {
          __hip_bfloat16* hrow = hb + (size_t)(bas + r) * H + colbase;
#pragma unroll
          for (int n = 0; n < NF; ++n)
            hrow[n * 16] = __float2bfloat16(fmaxf(acc[m][n][i] + bia[n], 0.f));
        } else {
          const int t = lst[r];
          const float s = ws->rv[t];
          float* orow = outp + (size_t)t * D + colbase;
#pragma unroll
          for (int n = 0; n < NF; ++n)
            orow[n * 16] = (acc[m][n][i] + bia[n]) * s;
        }
      }
    }
  }
}

__global__ void loss_k(const WS* __restrict__ ws, float* __restrict__ out) {
  if (threadIdx.x == 0 && blockIdx.x == 0) {
    float s = 0.f;
#pragma unroll
    for (int i = 0; i < 8; ++i) s += ((float)ws->counts[i] / (float)T) * ws->pi8[i];
    out[(size_t)T * D] = 0.01f * (float)E * s;
  }
}

}  // namespace

extern "C" void kernel_launch(void* const* d_in, const int* in_sizes, int n_in,
                              void* d_out, int out_size, void* d_ws, size_t ws_size,
                              hipStream_t stream) {
  const float* x  = (const float*)d_in[0];
  const float* Wg = (const float*)d_in[1];
  const float* bg = (const float*)d_in[2];
  const float* W1 = (const float*)d_in[3];
  const float* b1 = (const float*)d_in[4];
  const float* W2 = (const float*)d_in[5];
  const float* b2 = (const float*)d_in[6];
  float* out = (float*)d_out;
  WS* ws = (WS*)d_ws;
  char* wsb = (char*)d_ws;
  __hip_bfloat16* xb  = (__hip_bfloat16*)(wsb + XB_OFF);
  __hip_bfloat16* wt1 = (__hip_bfloat16*)(wsb + WT1_OFF);
  __hip_bfloat16* wt2 = (__hip_bfloat16*)(wsb + WT2_OFF);
  __hip_bfloat16* hbp = (__hip_bfloat16*)(wsb + HB_OFF);

  hipLaunchKernelGGL(init_k, dim3(1), dim3(64), 0, stream, ws);
  hipLaunchKernelGGL(route_k, dim3(T / 4), dim3(256), 0, stream, x, Wg, bg, xb, ws);
  hipLaunchKernelGGL(build_k, dim3(T / 256), dim3(256), 0, stream, ws);
  hipLaunchKernelGGL(prefix_k, dim3(1), dim3(64), 0, stream, ws);
  hipLaunchKernelGGL((cvt_t<D, H>), dim3(H / 64, D / 64, E), dim3(256), 0, stream, W1, wt1);
  hipLaunchKernelGGL((cvt_t<H, D>), dim3(D / 64, H / 64, E), dim3(256), 0, stream, W2, wt2);
  hipLaunchKernelGGL((mgemm<D, 128, 2, 2, false>), dim3(H / 128, 32, E), dim3(256), 0, stream,
                     xb, wt1, b1, hbp, nullptr, ws);
  hipLaunchKernelGGL((mgemm<H, 64, 4, 1, true>), dim3(D / 64, 32, E), dim3(256), 0, stream,
                     hbp, wt2, b2, nullptr, out, ws);
  hipLaunchKernelGGL(loss_k, dim3(1), dim3(1), 0, stream, ws, out);
}

// Round 7
// 200.112 us; speedup vs baseline: 1.3154x; 1.3154x over previous
//
#include <hip/hip_runtime.h>
#include <hip/hip_bf16.h>
#include <cstddef>
#include <cstdint>

// SwitchFFN: B=2,S=2048,D=512,E=8,H=2048. T=4096 tokens.
// Round 7 resubmit (round-6 bench was an acquisition timeout — no data).
// NO global atomics. route_k writes ridx/rv/pi8/xb only; single-block
// plan_k does LDS histogram + prefix + compact list + loss.
// Theory under test: R2/R4/R5's constant ~52-56us route_k was
// same-cache-line atomic serialization (4096 RMW x ~13.6ns ~= 56us).
//   route(+xb cvt) -> plan -> cvt(W1^T,W2^T) -> mgemm1 -> mgemm2

namespace {

constexpr int T = 4096;
constexpr int D = 512;
constexpr int E = 8;
constexpr int H = 2048;

typedef __attribute__((ext_vector_type(8))) short short8;
typedef __attribute__((ext_vector_type(4))) float f32x4;

struct WS {
  int   counts[8];
  int   base[8];
  float pi8[8];
  float rv[T];
  int   ridx[T];
  int   list[T];      // compact: expert e's tokens at [base[e], base[e]+counts[e])
};

constexpr size_t HDR     = (sizeof(WS) + 255) & ~size_t(255);
constexpr size_t XB_OFF  = HDR;                                      // bf16 x   [T][D]
constexpr size_t WT1_OFF = XB_OFF  + 2 * (size_t)T * D;              // bf16 W1^T [E][H][D]
constexpr size_t WT2_OFF = WT1_OFF + 2 * (size_t)E * H * D;          // bf16 W2^T [E][D][H]
constexpr size_t HB_OFF  = WT2_OFF + 2 * (size_t)E * D * H;          // bf16 h (compact) [T][H]

#define GLD16(g, l)                                                       \
  __builtin_amdgcn_global_load_lds(                                       \
      (const __attribute__((address_space(1))) void*)(g),                 \
      (__attribute__((address_space(3))) void*)(l), 16, 0, 0)

// One wave per token. Lane reads x[t][lane*8..+7] (coalesced), emits bf16 xb,
// computes 8 expert logits with a halving butterfly (10 shuffles), then a
// lane-parallel 8-wide softmax + 64-bit-key argmax (first-max semantics).
// NO atomics.
__global__ __launch_bounds__(256) void route_k(const float* __restrict__ x,
                                               const float* __restrict__ Wg,
                                               const float* __restrict__ bg,
                                               __hip_bfloat16* __restrict__ xb,
                                               WS* __restrict__ ws) {
  const int wave = threadIdx.x >> 6;
  const int lane = threadIdx.x & 63;
  const int t = blockIdx.x * 4 + wave;
  const float* xr = x + (size_t)t * D;

  // ---- load 8 consecutive x values, emit bf16 ----
  const float4* xp = reinterpret_cast<const float4*>(xr) + lane * 2;
  float4 a = xp[0], b4 = xp[1];
  float xs[8] = {a.x, a.y, a.z, a.w, b4.x, b4.y, b4.z, b4.w};
  alignas(16) __hip_bfloat16 o[8];
#pragma unroll
  for (int j = 0; j < 8; ++j) o[j] = __float2bfloat16(xs[j]);
  *reinterpret_cast<int4*>(xb + (size_t)t * D + lane * 8) = *reinterpret_cast<int4*>(o);

  // ---- partial logits: lane covers k = lane*8..lane*8+7, all 8 experts ----
  float acc[8] = {0.f, 0.f, 0.f, 0.f, 0.f, 0.f, 0.f, 0.f};
#pragma unroll
  for (int i = 0; i < 8; ++i) {
    const int k = lane * 8 + i;
    const float4* w = reinterpret_cast<const float4*>(Wg + (size_t)k * 8);
    float4 w0 = w[0], w1 = w[1];
    float xv = xs[i];
    acc[0] += xv * w0.x; acc[1] += xv * w0.y; acc[2] += xv * w0.z; acc[3] += xv * w0.w;
    acc[4] += xv * w1.x; acc[5] += xv * w1.y; acc[6] += xv * w1.z; acc[7] += xv * w1.w;
  }

  // ---- halving butterfly: 4+2+1 shuffles -> lane holds expert e(lane) ----
#pragma unroll
  for (int j = 0; j < 4; ++j) {
    float send = (lane & 1) ? acc[j] : acc[j + 4];
    float recv = __shfl_xor(send, 1, 64);
    acc[j] = ((lane & 1) ? acc[j + 4] : acc[j]) + recv;
  }
#pragma unroll
  for (int j = 0; j < 2; ++j) {
    float send = (lane & 2) ? acc[j] : acc[j + 2];
    float recv = __shfl_xor(send, 2, 64);
    acc[j] = ((lane & 2) ? acc[j + 2] : acc[j]) + recv;
  }
  {
    float send = (lane & 4) ? acc[0] : acc[1];
    float recv = __shfl_xor(send, 4, 64);
    acc[0] = ((lane & 4) ? acc[1] : acc[0]) + recv;
  }
  float v = acc[0];
  v += __shfl_xor(v, 8, 64);
  v += __shfl_xor(v, 16, 64);
  v += __shfl_xor(v, 32, 64);
  // expert owned by this lane (bit-reversed low-3 bits)
  const int e = 4 * (lane & 1) + 2 * ((lane >> 1) & 1) + ((lane >> 2) & 1);

  // ---- lane-parallel softmax over the 8-lane group ----
  float lg = v + bg[e];
  float m = lg;
  m = fmaxf(m, __shfl_xor(m, 1, 64));
  m = fmaxf(m, __shfl_xor(m, 2, 64));
  m = fmaxf(m, __shfl_xor(m, 4, 64));
  float p = expf(lg - m);
  float s = p;
  s += __shfl_xor(s, 1, 64);
  s += __shfl_xor(s, 2, 64);
  s += __shfl_xor(s, 4, 64);
  float pr = p / s;
  float psum = pr;
  psum += __shfl_xor(psum, 1, 64);
  psum += __shfl_xor(psum, 2, 64);
  psum += __shfl_xor(psum, 4, 64);
  // argmax with first-max (smallest e wins ties): key = bits(pr)<<8 | (7-e)
  unsigned long long key =
      ((unsigned long long)__float_as_uint(pr) << 8) | (unsigned)(7 - e);
  unsigned long long k2;
  k2 = __shfl_xor(key, 1, 64); key = key > k2 ? key : k2;
  k2 = __shfl_xor(key, 2, 64); key = key > k2 ? key : k2;
  k2 = __shfl_xor(key, 4, 64); key = key > k2 ? key : k2;

  if (lane == 0) {
    int ebest = 7 - (int)(key & 0xffull);
    float prmax = __uint_as_float((unsigned)(key >> 8));
    ws->rv[t] = prmax;
    ws->ridx[t] = ebest;
    if (t < 8) ws->pi8[t] = psum * 0.125f;
  }
}

// One block, 1024 threads: LDS histogram of ridx, prefix, compact list, loss.
__global__ __launch_bounds__(1024) void plan_k(WS* __restrict__ ws,
                                               float* __restrict__ out) {
  __shared__ int lcnt[8];
  __shared__ int lbase[8];
  const int tid = threadIdx.x;
  if (tid < 8) lcnt[tid] = 0;
  __syncthreads();
  int mye[4], mypos[4];
#pragma unroll
  for (int i = 0; i < 4; ++i) {
    int e = ws->ridx[tid + i * 1024];
    mye[i] = e;
    mypos[i] = atomicAdd(&lcnt[e], 1);  // LDS atomic
  }
  __syncthreads();
  if (tid == 0) {
    int b = 0;
    float s = 0.f;
#pragma unroll
    for (int e = 0; e < 8; ++e) {
      int c = lcnt[e];
      ws->counts[e] = c;
      ws->base[e] = b;
      lbase[e] = b;
      b += c;
      s += ((float)c / (float)T) * ws->pi8[e];
    }
    out[(size_t)T * D] = 0.01f * (float)E * s;
  }
  __syncthreads();
#pragma unroll
  for (int i = 0; i < 4; ++i)
    ws->list[lbase[mye[i]] + mypos[i]] = tid + i * 1024;
}

// in [E][K][N] f32 -> out [E][N][K] bf16 (64x64 LDS-tiled transpose+convert)
template <int K, int N>
__global__ __launch_bounds__(256) void cvt_t(const float* __restrict__ in,
                                             __hip_bfloat16* __restrict__ outp) {
  const int e = blockIdx.z;
  in   += (size_t)e * K * N;
  outp += (size_t)e * K * N;
  const int k0 = blockIdx.y * 64, n0 = blockIdx.x * 64;
  __shared__ __hip_bfloat16 tile[64][72];
  const int r = threadIdx.x >> 4, c = (threadIdx.x & 15) * 4;
#pragma unroll
  for (int rr = 0; rr < 4; ++rr) {
    float4 v = *reinterpret_cast<const float4*>(in + (size_t)(k0 + r + rr * 16) * N + n0 + c);
    tile[r + rr * 16][c + 0] = __float2bfloat16(v.x);
    tile[r + rr * 16][c + 1] = __float2bfloat16(v.y);
    tile[r + rr * 16][c + 2] = __float2bfloat16(v.z);
    tile[r + rr * 16][c + 3] = __float2bfloat16(v.w);
  }
  __syncthreads();
  const int n = threadIdx.x >> 2, ch = threadIdx.x & 3;
  alignas(16) __hip_bfloat16 o[16];
#pragma unroll
  for (int i = 0; i < 16; ++i) o[i] = tile[ch * 16 + i][n];
  __hip_bfloat16* dst = outp + (size_t)(n0 + n) * K + k0 + ch * 16;
  reinterpret_cast<int4*>(dst)[0] = reinterpret_cast<int4*>(o)[0];
  reinterpret_cast<int4*>(dst)[1] = reinterpret_cast<int4*>(o)[1];
}

// MFMA GEMM. BM=128, BK=64. A rows gathered (GEMM1) or compact (GEMM2).
// LDS tiles [rows][64] bf16 (128B rows, 8x16B chunks) with XOR chunk swizzle:
// chunk c of row r holds source chunk (c ^ (r&7)); reader applies same XOR.
template <int K, int BN, int WR, int WC, bool SECOND>
__global__ __launch_bounds__(256) void mgemm(const __hip_bfloat16* __restrict__ Ag,
                                             const __hip_bfloat16* __restrict__ Wt,
                                             const float* __restrict__ bias,
                                             __hip_bfloat16* __restrict__ hb,
                                             float* __restrict__ outp,
                                             WS* __restrict__ ws) {
  constexpr int BM = 128;
  constexpr int BK = 64;
  constexpr int NDIM = SECOND ? D : H;      // full N of this GEMM
  constexpr int MS = BM / WR, NS = BN / WC; // per-wave output span
  constexpr int MF = MS / 16, NF = NS / 16;
  constexpr int ACALLS = BM / 32;           // 4KB per global_load_lds round
  constexpr int BCALLS = BN / 32;

  const int e = blockIdx.z;
  const int cnt = ws->counts[e];
  const int m0 = blockIdx.y * BM;
  if (m0 >= cnt) return;
  const int n0 = blockIdx.x * BN;
  const int bas = ws->base[e];
  const int* lst = ws->list + bas;   // compact segment for expert e

  const int tid = threadIdx.x, lane = tid & 63, wave = tid >> 6;
  const int wr = wave / WC, wc = wave % WC;
  const int wrow = wr * MS, wcol = wc * NS;

  __shared__ unsigned char As[BM * 128];
  __shared__ unsigned char Bs[BN * 128];

  // staging source pointers (per thread, per 4KB call); row clamp for tails
  const int srow = tid >> 3;
  const int sj = tid & 7;
  const unsigned short* aptr[ACALLS];
#pragma unroll
  for (int q = 0; q < ACALLS; ++q) {
    int row = q * 32 + srow;
    int jj = sj ^ (row & 7);
    int mrow = m0 + row; if (mrow > cnt - 1) mrow = cnt - 1;
    int arow = SECOND ? (bas + mrow) : lst[mrow];
    aptr[q] = reinterpret_cast<const unsigned short*>(Ag) + (size_t)arow * K + jj * 8;
  }
  const unsigned short* bptr[BCALLS];
#pragma unroll
  for (int q = 0; q < BCALLS; ++q) {
    int row = q * 32 + srow;
    int jj = sj ^ (row & 7);
    bptr[q] = reinterpret_cast<const unsigned short*>(Wt) +
              ((size_t)e * NDIM + n0 + row) * K + jj * 8;
  }

  f32x4 acc[MF][NF] = {};

  for (int k0 = 0; k0 < K; k0 += BK) {
#pragma unroll
    for (int q = 0; q < ACALLS; ++q) GLD16(aptr[q] + k0, As + q * 4096 + (wave << 10));
#pragma unroll
    for (int q = 0; q < BCALLS; ++q) GLD16(bptr[q] + k0, Bs + q * 4096 + (wave << 10));
    __syncthreads();  // compiler drains vmcnt before barrier
#pragma unroll
    for (int s = 0; s < 2; ++s) {
      const int jA = s * 4 + (lane >> 4);
      short8 af[MF], bfr[NF];
#pragma unroll
      for (int m = 0; m < MF; ++m) {
        int row = wrow + m * 16 + (lane & 15);
        af[m] = *reinterpret_cast<const short8*>(As + row * 128 + ((jA ^ (row & 7)) << 4));
      }
#pragma unroll
      for (int n = 0; n < NF; ++n) {
        int row = wcol + n * 16 + (lane & 15);
        bfr[n] = *reinterpret_cast<const short8*>(Bs + row * 128 + ((jA ^ (row & 7)) << 4));
      }
#pragma unroll
      for (int m = 0; m < MF; ++m)
#pragma unroll
        for (int n = 0; n < NF; ++n)
          acc[m][n] = __builtin_amdgcn_mfma_f32_16x16x32_bf16(af[m], bfr[n], acc[m][n], 0, 0, 0);
    }
    __syncthreads();  // reads done before next stage overwrites
  }

  // epilogue — C/D map: col = lane&15, row = (lane>>4)*4 + i
  const int colbase = n0 + wcol + (lane & 15);
  float bia[NF];
#pragma unroll
  for (int n = 0; n < NF; ++n) bia[n] = bias[(size_t)e * NDIM + colbase + n * 16];
#pragma unroll
  for (int m = 0; m < MF; ++m) {
    const int rloc = wrow + m * 16 + ((lane >> 4) << 2);
#pragma unroll
    for (int i = 0; i < 4; ++i) {
      const int r = m0 + rloc + i;
      if (r < cnt) {
        if (!SECOND) {
          __hip_bfloat16* hrow = hb + (size_t)(bas + r) * H + colbase;
#pragma unroll
          for (int n = 0; n < NF; ++n)
            hrow[n * 16] = __float2bfloat16(fmaxf(acc[m][n][i] + bia[n], 0.f));
        } else {
          const int t = lst[r];
          const float s = ws->rv[t];
          float* orow = outp + (size_t)t * D + colbase;
#pragma unroll
          for (int n = 0; n < NF; ++n)
            orow[n * 16] = (acc[m][n][i] + bia[n]) * s;
        }
      }
    }
  }
}

}  // namespace

extern "C" void kernel_launch(void* const* d_in, const int* in_sizes, int n_in,
                              void* d_out, int out_size, void* d_ws, size_t ws_size,
                              hipStream_t stream) {
  const float* x  = (const float*)d_in[0];
  const float* Wg = (const float*)d_in[1];
  const float* bg = (const float*)d_in[2];
  const float* W1 = (const float*)d_in[3];
  const float* b1 = (const float*)d_in[4];
  const float* W2 = (const float*)d_in[5];
  const float* b2 = (const float*)d_in[6];
  float* out = (float*)d_out;
  WS* ws = (WS*)d_ws;
  char* wsb = (char*)d_ws;
  __hip_bfloat16* xb  = (__hip_bfloat16*)(wsb + XB_OFF);
  __hip_bfloat16* wt1 = (__hip_bfloat16*)(wsb + WT1_OFF);
  __hip_bfloat16* wt2 = (__hip_bfloat16*)(wsb + WT2_OFF);
  __hip_bfloat16* hbp = (__hip_bfloat16*)(wsb + HB_OFF);

  hipLaunchKernelGGL(route_k, dim3(T / 4), dim3(256), 0, stream, x, Wg, bg, xb, ws);
  hipLaunchKernelGGL(plan_k, dim3(1), dim3(1024), 0, stream, ws, out);
  hipLaunchKernelGGL((cvt_t<D, H>), dim3(H / 64, D / 64, E), dim3(256), 0, stream, W1, wt1);
  hipLaunchKernelGGL((cvt_t<H, D>), dim3(D / 64, H / 64, E), dim3(256), 0, stream, W2, wt2);
  hipLaunchKernelGGL((mgemm<D, 128, 2, 2, false>), dim3(H / 128, 32, E), dim3(256), 0, stream,
                     xb, wt1, b1, hbp, nullptr, ws);
  hipLaunchKernelGGL((mgemm<H, 64, 4, 1, true>), dim3(D / 64, 32, E), dim3(256), 0, stream,
                     hbp, wt2, b2, nullptr, out, ws);
}

// Round 10
// 188.773 us; speedup vs baseline: 1.3944x; 1.0601x over previous
//
#include <hip/hip_runtime.h>
#include <hip/hip_bf16.h>
#include <cstddef>
#include <cstdint>

// SwitchFFN: B=2,S=2048,D=512,E=8,H=2048. T=4096 tokens.
// Round 10 resubmit (rounds 8 and 9 were acquisition timeouts — no data).
// Occupancy round. GEMM2: BM=64 + split-K=2 + f32-atomic epilogue
// (prefill_k writes bias*rv). GEMM1: BM=64. cvt_t: f32 padded-LDS transpose.
//   route(+xb cvt) -> plan -> prefill -> cvt(W1^T,W2^T) -> mgemm1 -> mgemm2

namespace {

constexpr int T = 4096;
constexpr int D = 512;
constexpr int E = 8;
constexpr int H = 2048;

typedef __attribute__((ext_vector_type(8))) short short8;
typedef __attribute__((ext_vector_type(4))) float f32x4;

struct WS {
  int   counts[8];
  int   base[8];
  float pi8[8];
  float rv[T];
  int   ridx[T];
  int   list[T];      // compact: expert e's tokens at [base[e], base[e]+counts[e])
};

constexpr size_t HDR     = (sizeof(WS) + 255) & ~size_t(255);
constexpr size_t XB_OFF  = HDR;                                      // bf16 x   [T][D]
constexpr size_t WT1_OFF = XB_OFF  + 2 * (size_t)T * D;              // bf16 W1^T [E][H][D]
constexpr size_t WT2_OFF = WT1_OFF + 2 * (size_t)E * H * D;          // bf16 W2^T [E][D][H]
constexpr size_t HB_OFF  = WT2_OFF + 2 * (size_t)E * D * H;          // bf16 h (compact) [T][H]

#define GLD16(g, l)                                                       \
  __builtin_amdgcn_global_load_lds(                                       \
      (const __attribute__((address_space(1))) void*)(g),                 \
      (__attribute__((address_space(3))) void*)(l), 16, 0, 0)

// One wave per token. Lane reads x[t][lane*8..+7] (coalesced), emits bf16 xb,
// computes 8 expert logits with a halving butterfly (10 shuffles), then a
// lane-parallel 8-wide softmax + 64-bit-key argmax (first-max semantics).
// NO atomics.
__global__ __launch_bounds__(256) void route_k(const float* __restrict__ x,
                                               const float* __restrict__ Wg,
                                               const float* __restrict__ bg,
                                               __hip_bfloat16* __restrict__ xb,
                                               WS* __restrict__ ws) {
  const int wave = threadIdx.x >> 6;
  const int lane = threadIdx.x & 63;
  const int t = blockIdx.x * 4 + wave;
  const float* xr = x + (size_t)t * D;

  // ---- load 8 consecutive x values, emit bf16 ----
  const float4* xp = reinterpret_cast<const float4*>(xr) + lane * 2;
  float4 a = xp[0], b4 = xp[1];
  float xs[8] = {a.x, a.y, a.z, a.w, b4.x, b4.y, b4.z, b4.w};
  alignas(16) __hip_bfloat16 o[8];
#pragma unroll
  for (int j = 0; j < 8; ++j) o[j] = __float2bfloat16(xs[j]);
  *reinterpret_cast<int4*>(xb + (size_t)t * D + lane * 8) = *reinterpret_cast<int4*>(o);

  // ---- partial logits: lane covers k = lane*8..lane*8+7, all 8 experts ----
  float acc[8] = {0.f, 0.f, 0.f, 0.f, 0.f, 0.f, 0.f, 0.f};
#pragma unroll
  for (int i = 0; i < 8; ++i) {
    const int k = lane * 8 + i;
    const float4* w = reinterpret_cast<const float4*>(Wg + (size_t)k * 8);
    float4 w0 = w[0], w1 = w[1];
    float xv = xs[i];
    acc[0] += xv * w0.x; acc[1] += xv * w0.y; acc[2] += xv * w0.z; acc[3] += xv * w0.w;
    acc[4] += xv * w1.x; acc[5] += xv * w1.y; acc[6] += xv * w1.z; acc[7] += xv * w1.w;
  }

  // ---- halving butterfly: 4+2+1 shuffles -> lane holds expert e(lane) ----
#pragma unroll
  for (int j = 0; j < 4; ++j) {
    float send = (lane & 1) ? acc[j] : acc[j + 4];
    float recv = __shfl_xor(send, 1, 64);
    acc[j] = ((lane & 1) ? acc[j + 4] : acc[j]) + recv;
  }
#pragma unroll
  for (int j = 0; j < 2; ++j) {
    float send = (lane & 2) ? acc[j] : acc[j + 2];
    float recv = __shfl_xor(send, 2, 64);
    acc[j] = ((lane & 2) ? acc[j + 2] : acc[j]) + recv;
  }
  {
    float send = (lane & 4) ? acc[0] : acc[1];
    float recv = __shfl_xor(send, 4, 64);
    acc[0] = ((lane & 4) ? acc[1] : acc[0]) + recv;
  }
  float v = acc[0];
  v += __shfl_xor(v, 8, 64);
  v += __shfl_xor(v, 16, 64);
  v += __shfl_xor(v, 32, 64);
  // expert owned by this lane (bit-reversed low-3 bits)
  const int e = 4 * (lane & 1) + 2 * ((lane >> 1) & 1) + ((lane >> 2) & 1);

  // ---- lane-parallel softmax over the 8-lane group ----
  float lg = v + bg[e];
  float m = lg;
  m = fmaxf(m, __shfl_xor(m, 1, 64));
  m = fmaxf(m, __shfl_xor(m, 2, 64));
  m = fmaxf(m, __shfl_xor(m, 4, 64));
  float p = expf(lg - m);
  float s = p;
  s += __shfl_xor(s, 1, 64);
  s += __shfl_xor(s, 2, 64);
  s += __shfl_xor(s, 4, 64);
  float pr = p / s;
  float psum = pr;
  psum += __shfl_xor(psum, 1, 64);
  psum += __shfl_xor(psum, 2, 64);
  psum += __shfl_xor(psum, 4, 64);
  // argmax with first-max (smallest e wins ties): key = bits(pr)<<8 | (7-e)
  unsigned long long key =
      ((unsigned long long)__float_as_uint(pr) << 8) | (unsigned)(7 - e);
  unsigned long long k2;
  k2 = __shfl_xor(key, 1, 64); key = key > k2 ? key : k2;
  k2 = __shfl_xor(key, 2, 64); key = key > k2 ? key : k2;
  k2 = __shfl_xor(key, 4, 64); key = key > k2 ? key : k2;

  if (lane == 0) {
    int ebest = 7 - (int)(key & 0xffull);
    float prmax = __uint_as_float((unsigned)(key >> 8));
    ws->rv[t] = prmax;
    ws->ridx[t] = ebest;
    if (t < 8) ws->pi8[t] = psum * 0.125f;
  }
}

// One block, 1024 threads: LDS histogram of ridx, prefix, compact list, loss.
__global__ __launch_bounds__(1024) void plan_k(WS* __restrict__ ws,
                                               float* __restrict__ out) {
  __shared__ int lcnt[8];
  __shared__ int lbase[8];
  const int tid = threadIdx.x;
  if (tid < 8) lcnt[tid] = 0;
  __syncthreads();
  int mye[4], mypos[4];
#pragma unroll
  for (int i = 0; i < 4; ++i) {
    int e = ws->ridx[tid + i * 1024];
    mye[i] = e;
    mypos[i] = atomicAdd(&lcnt[e], 1);  // LDS atomic
  }
  __syncthreads();
  if (tid == 0) {
    int b = 0;
    float s = 0.f;
#pragma unroll
    for (int e = 0; e < 8; ++e) {
      int c = lcnt[e];
      ws->counts[e] = c;
      ws->base[e] = b;
      lbase[e] = b;
      b += c;
      s += ((float)c / (float)T) * ws->pi8[e];
    }
    out[(size_t)T * D] = 0.01f * (float)E * s;
  }
  __syncthreads();
#pragma unroll
  for (int i = 0; i < 4; ++i)
    ws->list[lbase[mye[i]] + mypos[i]] = tid + i * 1024;
}

// out[t][d] = b2[e(t)][d] * rv[t]   (4 floats/thread; GEMM2 atomically adds on top)
__global__ __launch_bounds__(256) void prefill_k(const float* __restrict__ b2,
                                                 const WS* __restrict__ ws,
                                                 float* __restrict__ out) {
  const int idx = blockIdx.x * 256 + threadIdx.x;
  const int t = idx >> 7;            // D/4 = 128 chunks per row
  const int d = (idx & 127) * 4;
  const float rvv = ws->rv[t];
  const int e = ws->ridx[t];
  float4 b = *reinterpret_cast<const float4*>(b2 + (size_t)e * D + d);
  float4 r;
  r.x = b.x * rvv; r.y = b.y * rvv; r.z = b.z * rvv; r.w = b.w * rvv;
  *reinterpret_cast<float4*>(out + (size_t)t * D + d) = r;
}

// in [E][K][N] f32 -> out [E][N][K] bf16. f32 LDS tile with +1 pad (2-way max).
template <int K, int N>
__global__ __launch_bounds__(256) void cvt_t(const float* __restrict__ in,
                                             __hip_bfloat16* __restrict__ outp) {
  const int e = blockIdx.z;
  in   += (size_t)e * K * N;
  outp += (size_t)e * K * N;
  const int k0 = blockIdx.y * 64, n0 = blockIdx.x * 64;
  __shared__ float tile[64][65];
  const int r = threadIdx.x >> 4, c = (threadIdx.x & 15) * 4;
#pragma unroll
  for (int rr = 0; rr < 4; ++rr) {
    float4 v = *reinterpret_cast<const float4*>(in + (size_t)(k0 + r + rr * 16) * N + n0 + c);
    tile[r + rr * 16][c + 0] = v.x;
    tile[r + rr * 16][c + 1] = v.y;
    tile[r + rr * 16][c + 2] = v.z;
    tile[r + rr * 16][c + 3] = v.w;
  }
  __syncthreads();
  const int n = threadIdx.x >> 2, kc = threadIdx.x & 3;
  alignas(16) __hip_bfloat16 o[16];
#pragma unroll
  for (int i = 0; i < 16; ++i) o[i] = __float2bfloat16(tile[kc * 16 + i][n]);
  __hip_bfloat16* dst = outp + (size_t)(n0 + n) * K + k0 + kc * 16;
  reinterpret_cast<int4*>(dst)[0] = reinterpret_cast<int4*>(o)[0];
  reinterpret_cast<int4*>(dst)[1] = reinterpret_cast<int4*>(o)[1];
}

// MFMA GEMM. BM=64, BK=64. A rows gathered (GEMM1) or compact (GEMM2).
// LDS tiles [rows][64] bf16 (128B rows, 8x16B chunks) with XOR chunk swizzle.
// KSPLIT>1: blockIdx.z = e*KSPLIT+kz, each kz covers K/KSPLIT; epilogue is
// f32 atomic add into pre-filled out (bias*rv already there).
template <int K, int BM, int BN, int WR, int WC, int KSPLIT, bool SECOND>
__global__ __launch_bounds__(256) void mgemm(const __hip_bfloat16* __restrict__ Ag,
                                             const __hip_bfloat16* __restrict__ Wt,
                                             const float* __restrict__ bias,
                                             __hip_bfloat16* __restrict__ hb,
                                             float* __restrict__ outp,
                                             WS* __restrict__ ws) {
  constexpr int BK = 64;
  constexpr int NDIM = SECOND ? D : H;      // full N of this GEMM
  constexpr int MS = BM / WR, NS = BN / WC; // per-wave output span
  constexpr int MF = MS / 16, NF = NS / 16;
  constexpr int ACALLS = BM / 32;           // 4KB per global_load_lds round
  constexpr int BCALLS = BN / 32;
  constexpr int KCH = K / KSPLIT;

  const int e = blockIdx.z / KSPLIT;
  const int kz = blockIdx.z % KSPLIT;
  const int cnt = ws->counts[e];
  const int m0 = blockIdx.y * BM;
  if (m0 >= cnt) return;
  const int n0 = blockIdx.x * BN;
  const int bas = ws->base[e];
  const int* lst = ws->list + bas;   // compact segment for expert e

  const int tid = threadIdx.x, lane = tid & 63, wave = tid >> 6;
  const int wr = wave / WC, wc = wave % WC;
  const int wrow = wr * MS, wcol = wc * NS;

  __shared__ unsigned char As[BM * 128];
  __shared__ unsigned char Bs[BN * 128];

  // staging source pointers (per thread, per 4KB call); row clamp for tails
  const int srow = tid >> 3;
  const int sj = tid & 7;
  const unsigned short* aptr[ACALLS];
#pragma unroll
  for (int q = 0; q < ACALLS; ++q) {
    int row = q * 32 + srow;
    int jj = sj ^ (row & 7);
    int mrow = m0 + row; if (mrow > cnt - 1) mrow = cnt - 1;
    int arow = SECOND ? (bas + mrow) : lst[mrow];
    aptr[q] = reinterpret_cast<const unsigned short*>(Ag) + (size_t)arow * K + jj * 8;
  }
  const unsigned short* bptr[BCALLS];
#pragma unroll
  for (int q = 0; q < BCALLS; ++q) {
    int row = q * 32 + srow;
    int jj = sj ^ (row & 7);
    bptr[q] = reinterpret_cast<const unsigned short*>(Wt) +
              ((size_t)e * NDIM + n0 + row) * K + jj * 8;
  }

  f32x4 acc[MF][NF] = {};

  for (int k0 = kz * KCH; k0 < (kz + 1) * KCH; k0 += BK) {
#pragma unroll
    for (int q = 0; q < ACALLS; ++q) GLD16(aptr[q] + k0, As + q * 4096 + (wave << 10));
#pragma unroll
    for (int q = 0; q < BCALLS; ++q) GLD16(bptr[q] + k0, Bs + q * 4096 + (wave << 10));
    __syncthreads();  // compiler drains vmcnt before barrier
#pragma unroll
    for (int s = 0; s < 2; ++s) {
      const int jA = s * 4 + (lane >> 4);
      short8 af[MF], bfr[NF];
#pragma unroll
      for (int m = 0; m < MF; ++m) {
        int row = wrow + m * 16 + (lane & 15);
        af[m] = *reinterpret_cast<const short8*>(As + row * 128 + ((jA ^ (row & 7)) << 4));
      }
#pragma unroll
      for (int n = 0; n < NF; ++n) {
        int row = wcol + n * 16 + (lane & 15);
        bfr[n] = *reinterpret_cast<const short8*>(Bs + row * 128 + ((jA ^ (row & 7)) << 4));
      }
#pragma unroll
      for (int m = 0; m < MF; ++m)
#pragma unroll
        for (int n = 0; n < NF; ++n)
          acc[m][n] = __builtin_amdgcn_mfma_f32_16x16x32_bf16(af[m], bfr[n], acc[m][n], 0, 0, 0);
    }
    __syncthreads();  // reads done before next stage overwrites
  }

  // epilogue — C/D map: col = lane&15, row = (lane>>4)*4 + i
  const int colbase = n0 + wcol + (lane & 15);
  float bia[NF];
  if (!SECOND) {
#pragma unroll
    for (int n = 0; n < NF; ++n) bia[n] = bias[(size_t)e * NDIM + colbase + n * 16];
  }
#pragma unroll
  for (int m = 0; m < MF; ++m) {
    const int rloc = wrow + m * 16 + ((lane >> 4) << 2);
#pragma unroll
    for (int i = 0; i < 4; ++i) {
      const int r = m0 + rloc + i;
      if (r < cnt) {
        if (!SECOND) {
          __hip_bfloat16* hrow = hb + (size_t)(bas + r) * H + colbase;
#pragma unroll
          for (int n = 0; n < NF; ++n)
            hrow[n * 16] = __float2bfloat16(fmaxf(acc[m][n][i] + bia[n], 0.f));
        } else {
          const int t = lst[r];
          const float sc = ws->rv[t];
          float* orow = outp + (size_t)t * D + colbase;
#pragma unroll
          for (int n = 0; n < NF; ++n)
            unsafeAtomicAdd(orow + n * 16, acc[m][n][i] * sc);
        }
      }
    }
  }
}

}  // namespace

extern "C" void kernel_launch(void* const* d_in, const int* in_sizes, int n_in,
                              void* d_out, int out_size, void* d_ws, size_t ws_size,
                              hipStream_t stream) {
  const float* x  = (const float*)d_in[0];
  const float* Wg = (const float*)d_in[1];
  const float* bg = (const float*)d_in[2];
  const float* W1 = (const float*)d_in[3];
  const float* b1 = (const float*)d_in[4];
  const float* W2 = (const float*)d_in[5];
  const float* b2 = (const float*)d_in[6];
  float* out = (float*)d_out;
  WS* ws = (WS*)d_ws;
  char* wsb = (char*)d_ws;
  __hip_bfloat16* xb  = (__hip_bfloat16*)(wsb + XB_OFF);
  __hip_bfloat16* wt1 = (__hip_bfloat16*)(wsb + WT1_OFF);
  __hip_bfloat16* wt2 = (__hip_bfloat16*)(wsb + WT2_OFF);
  __hip_bfloat16* hbp = (__hip_bfloat16*)(wsb + HB_OFF);

  hipLaunchKernelGGL(route_k, dim3(T / 4), dim3(256), 0, stream, x, Wg, bg, xb, ws);
  hipLaunchKernelGGL(plan_k, dim3(1), dim3(1024), 0, stream, ws, out);
  hipLaunchKernelGGL(prefill_k, dim3(T * D / 1024), dim3(256), 0, stream, b2, ws, out);
  hipLaunchKernelGGL((cvt_t<D, H>), dim3(H / 64, D / 64, E), dim3(256), 0, stream, W1, wt1);
  hipLaunchKernelGGL((cvt_t<H, D>), dim3(D / 64, H / 64, E), dim3(256), 0, stream, W2, wt2);
  hipLaunchKernelGGL((mgemm<D, 64, 128, 2, 2, 1, false>), dim3(H / 128, T / 64, E),
                     dim3(256), 0, stream, xb, wt1, b1, hbp, nullptr, ws);
  hipLaunchKernelGGL((mgemm<H, 64, 64, 2, 2, 2, true>), dim3(D / 64, T / 64, E * 2),
                     dim3(256), 0, stream, hbp, wt2, b2, nullptr, out, ws);
}

// Round 11
// 173.315 us; speedup vs baseline: 1.5188x; 1.0892x over previous
//
#include <hip/hip_runtime.h>
#include <hip/hip_bf16.h>
#include <cstddef>
#include <cstdint>

// SwitchFFN: B=2,S=2048,D=512,E=8,H=2048. T=4096 tokens.
// Round 11: expert->XCD pinning (flat grid, e = flat&7 so expert e's blocks
// land on XCD e; its 2MB W-slice + activations become L2-resident).
// prefill folded into route_k (all lanes know argmax). cvt_t W1+W2 merged.
// 5 dispatches: route(+out prefill+xb) -> plan -> cvt_both -> mgemm1 -> mgemm2

namespace {

constexpr int T = 4096;
constexpr int D = 512;
constexpr int E = 8;
constexpr int H = 2048;

typedef __attribute__((ext_vector_type(8))) short short8;
typedef __attribute__((ext_vector_type(4))) float f32x4;

struct WS {
  int   counts[8];
  int   base[8];
  float pi8[8];
  float rv[T];
  int   ridx[T];
  int   list[T];      // compact: expert e's tokens at [base[e], base[e]+counts[e])
};

constexpr size_t HDR     = (sizeof(WS) + 255) & ~size_t(255);
constexpr size_t XB_OFF  = HDR;                                      // bf16 x   [T][D]
constexpr size_t WT1_OFF = XB_OFF  + 2 * (size_t)T * D;              // bf16 W1^T [E][H][D]
constexpr size_t WT2_OFF = WT1_OFF + 2 * (size_t)E * H * D;          // bf16 W2^T [E][D][H]
constexpr size_t HB_OFF  = WT2_OFF + 2 * (size_t)E * D * H;          // bf16 h (compact) [T][H]

#define GLD16(g, l)                                                       \
  __builtin_amdgcn_global_load_lds(                                       \
      (const __attribute__((address_space(1))) void*)(g),                 \
      (__attribute__((address_space(3))) void*)(l), 16, 0, 0)

// One wave per token. Lane reads x[t][lane*8..+7] (coalesced), emits bf16 xb,
// computes 8 expert logits with a halving butterfly, lane-parallel softmax +
// wave-uniform argmax; then the whole wave prefills out[t][*] = b2[e*]*rv.
__global__ __launch_bounds__(256) void route_k(const float* __restrict__ x,
                                               const float* __restrict__ Wg,
                                               const float* __restrict__ bg,
                                               const float* __restrict__ b2,
                                               __hip_bfloat16* __restrict__ xb,
                                               float* __restrict__ out,
                                               WS* __restrict__ ws) {
  const int wave = threadIdx.x >> 6;
  const int lane = threadIdx.x & 63;
  const int t = blockIdx.x * 4 + wave;
  const float* xr = x + (size_t)t * D;

  // ---- load 8 consecutive x values, emit bf16 ----
  const float4* xp = reinterpret_cast<const float4*>(xr) + lane * 2;
  float4 a = xp[0], b4 = xp[1];
  float xs[8] = {a.x, a.y, a.z, a.w, b4.x, b4.y, b4.z, b4.w};
  alignas(16) __hip_bfloat16 o[8];
#pragma unroll
  for (int j = 0; j < 8; ++j) o[j] = __float2bfloat16(xs[j]);
  *reinterpret_cast<int4*>(xb + (size_t)t * D + lane * 8) = *reinterpret_cast<int4*>(o);

  // ---- partial logits: lane covers k = lane*8..lane*8+7, all 8 experts ----
  float acc[8] = {0.f, 0.f, 0.f, 0.f, 0.f, 0.f, 0.f, 0.f};
#pragma unroll
  for (int i = 0; i < 8; ++i) {
    const int k = lane * 8 + i;
    const float4* w = reinterpret_cast<const float4*>(Wg + (size_t)k * 8);
    float4 w0 = w[0], w1 = w[1];
    float xv = xs[i];
    acc[0] += xv * w0.x; acc[1] += xv * w0.y; acc[2] += xv * w0.z; acc[3] += xv * w0.w;
    acc[4] += xv * w1.x; acc[5] += xv * w1.y; acc[6] += xv * w1.z; acc[7] += xv * w1.w;
  }

  // ---- halving butterfly: 4+2+1 shuffles -> lane holds expert e(lane) ----
#pragma unroll
  for (int j = 0; j < 4; ++j) {
    float send = (lane & 1) ? acc[j] : acc[j + 4];
    float recv = __shfl_xor(send, 1, 64);
    acc[j] = ((lane & 1) ? acc[j + 4] : acc[j]) + recv;
  }
#pragma unroll
  for (int j = 0; j < 2; ++j) {
    float send = (lane & 2) ? acc[j] : acc[j + 2];
    float recv = __shfl_xor(send, 2, 64);
    acc[j] = ((lane & 2) ? acc[j + 2] : acc[j]) + recv;
  }
  {
    float send = (lane & 4) ? acc[0] : acc[1];
    float recv = __shfl_xor(send, 4, 64);
    acc[0] = ((lane & 4) ? acc[1] : acc[0]) + recv;
  }
  float v = acc[0];
  v += __shfl_xor(v, 8, 64);
  v += __shfl_xor(v, 16, 64);
  v += __shfl_xor(v, 32, 64);
  // expert owned by this lane (bit-reversed low-3 bits); identical across 8-groups
  const int e = 4 * (lane & 1) + 2 * ((lane >> 1) & 1) + ((lane >> 2) & 1);

  // ---- lane-parallel softmax over the 8-lane group ----
  float lg = v + bg[e];
  float m = lg;
  m = fmaxf(m, __shfl_xor(m, 1, 64));
  m = fmaxf(m, __shfl_xor(m, 2, 64));
  m = fmaxf(m, __shfl_xor(m, 4, 64));
  float p = expf(lg - m);
  float s = p;
  s += __shfl_xor(s, 1, 64);
  s += __shfl_xor(s, 2, 64);
  s += __shfl_xor(s, 4, 64);
  float pr = p / s;
  float psum = pr;
  psum += __shfl_xor(psum, 1, 64);
  psum += __shfl_xor(psum, 2, 64);
  psum += __shfl_xor(psum, 4, 64);
  // argmax with first-max (smallest e wins ties): key = bits(pr)<<8 | (7-e)
  unsigned long long key =
      ((unsigned long long)__float_as_uint(pr) << 8) | (unsigned)(7 - e);
  unsigned long long k2;
  k2 = __shfl_xor(key, 1, 64); key = key > k2 ? key : k2;
  k2 = __shfl_xor(key, 2, 64); key = key > k2 ? key : k2;
  k2 = __shfl_xor(key, 4, 64); key = key > k2 ? key : k2;
  // key (and psum) are wave-uniform here: v was reduced over the full wave,
  // so every 8-lane group computed identical values.
  const int ebest = 7 - (int)(key & 0xffull);
  const float prmax = __uint_as_float((unsigned)(key >> 8));

  // ---- prefill out[t][*] = b2[ebest][*] * prmax (mgemm2 atomic-adds on top) ----
  const float4* bp = reinterpret_cast<const float4*>(b2 + (size_t)ebest * D) + lane * 2;
  float4 q0 = bp[0], q1 = bp[1];
  float4 r0, r1;
  r0.x = q0.x * prmax; r0.y = q0.y * prmax; r0.z = q0.z * prmax; r0.w = q0.w * prmax;
  r1.x = q1.x * prmax; r1.y = q1.y * prmax; r1.z = q1.z * prmax; r1.w = q1.w * prmax;
  float4* op = reinterpret_cast<float4*>(out + (size_t)t * D) + lane * 2;
  op[0] = r0; op[1] = r1;

  if (lane == 0) {
    ws->rv[t] = prmax;
    ws->ridx[t] = ebest;
    if (t < 8) ws->pi8[t] = psum * 0.125f;
  }
}

// One block, 1024 threads: LDS histogram of ridx, prefix, compact list, loss.
__global__ __launch_bounds__(1024) void plan_k(WS* __restrict__ ws,
                                               float* __restrict__ out) {
  __shared__ int lcnt[8];
  __shared__ int lbase[8];
  const int tid = threadIdx.x;
  if (tid < 8) lcnt[tid] = 0;
  __syncthreads();
  int mye[4], mypos[4];
#pragma unroll
  for (int i = 0; i < 4; ++i) {
    int e = ws->ridx[tid + i * 1024];
    mye[i] = e;
    mypos[i] = atomicAdd(&lcnt[e], 1);  // LDS atomic
  }
  __syncthreads();
  if (tid == 0) {
    int b = 0;
    float s = 0.f;
#pragma unroll
    for (int e = 0; e < 8; ++e) {
      int c = lcnt[e];
      ws->counts[e] = c;
      ws->base[e] = b;
      lbase[e] = b;
      b += c;
      s += ((float)c / (float)T) * ws->pi8[e];
    }
    out[(size_t)T * D] = 0.01f * (float)E * s;
  }
  __syncthreads();
#pragma unroll
  for (int i = 0; i < 4; ++i)
    ws->list[lbase[mye[i]] + mypos[i]] = tid + i * 1024;
}

// 64x64 transpose+convert body: in [E][K][N] f32 slice -> out [E][N][K] bf16.
template <int K, int N>
__device__ void cvt_body(const float* __restrict__ in,
                         __hip_bfloat16* __restrict__ outp,
                         int e, int kt, int nt, float (*tile)[65]) {
  in   += (size_t)e * K * N;
  outp += (size_t)e * K * N;
  const int k0 = kt * 64, n0 = nt * 64;
  const int r = threadIdx.x >> 4, c = (threadIdx.x & 15) * 4;
#pragma unroll
  for (int rr = 0; rr < 4; ++rr) {
    float4 v = *reinterpret_cast<const float4*>(in + (size_t)(k0 + r + rr * 16) * N + n0 + c);
    tile[r + rr * 16][c + 0] = v.x;
    tile[r + rr * 16][c + 1] = v.y;
    tile[r + rr * 16][c + 2] = v.z;
    tile[r + rr * 16][c + 3] = v.w;
  }
  __syncthreads();
  const int n = threadIdx.x >> 2, kc = threadIdx.x & 3;
  alignas(16) __hip_bfloat16 o[16];
#pragma unroll
  for (int i = 0; i < 16; ++i) o[i] = __float2bfloat16(tile[kc * 16 + i][n]);
  __hip_bfloat16* dst = outp + (size_t)(n0 + n) * K + k0 + kc * 16;
  reinterpret_cast<int4*>(dst)[0] = reinterpret_cast<int4*>(o)[0];
  reinterpret_cast<int4*>(dst)[1] = reinterpret_cast<int4*>(o)[1];
}

// z<8: W1 [512][2048] (x=n-tile of 32, y=k-tile of 8).
// z>=8: W2 [2048][512] (x=k-tile of 32, y=n-tile of 8).
__global__ __launch_bounds__(256) void cvt_both(const float* __restrict__ W1,
                                                const float* __restrict__ W2,
                                                __hip_bfloat16* __restrict__ wt1,
                                                __hip_bfloat16* __restrict__ wt2) {
  __shared__ float tile[64][65];
  if (blockIdx.z < 8)
    cvt_body<D, H>(W1, wt1, blockIdx.z, blockIdx.y, blockIdx.x, tile);
  else
    cvt_body<H, D>(W2, wt2, blockIdx.z - 8, blockIdx.x, blockIdx.y, tile);
}

// MFMA GEMM, flat 1-D grid with expert in the low 3 bits -> expert e's blocks
// all land on XCD e (native wgid%8 round-robin) so its W/activation slices
// stay L2-resident. BM=64, BK=64. LDS rows XOR-chunk-swizzled.
// KSPLIT>1: f32 atomic-add epilogue into pre-filled out.
template <int K, int BM, int BN, int WR, int WC, int KSPLIT, bool SECOND>
__global__ __launch_bounds__(256) void mgemm(const __hip_bfloat16* __restrict__ Ag,
                                             const __hip_bfloat16* __restrict__ Wt,
                                             const float* __restrict__ bias,
                                             __hip_bfloat16* __restrict__ hb,
                                             float* __restrict__ outp,
                                             WS* __restrict__ ws) {
  constexpr int BK = 64;
  constexpr int NDIM = SECOND ? D : H;      // full N of this GEMM
  constexpr int NXT = NDIM / BN;
  constexpr int MS = BM / WR, NS = BN / WC; // per-wave output span
  constexpr int MF = MS / 16, NF = NS / 16;
  constexpr int ACALLS = BM / 32;           // 4KB per global_load_lds round
  constexpr int BCALLS = BN / 32;
  constexpr int KCH = K / KSPLIT;

  const int flat = blockIdx.x;
  const int e = flat & 7;                    // low 3 bits -> XCD id
  int q = flat >> 3;
  const int kz = q % KSPLIT; q /= KSPLIT;
  const int n_i = q % NXT;
  const int y_i = q / NXT;

  const int cnt = ws->counts[e];
  const int m0 = y_i * BM;
  if (m0 >= cnt) return;
  const int n0 = n_i * BN;
  const int bas = ws->base[e];
  const int* lst = ws->list + bas;   // compact segment for expert e

  const int tid = threadIdx.x, lane = tid & 63, wave = tid >> 6;
  const int wr = wave / WC, wc = wave % WC;
  const int wrow = wr * MS, wcol = wc * NS;

  __shared__ unsigned char As[BM * 128];
  __shared__ unsigned char Bs[BN * 128];

  // staging source pointers (per thread, per 4KB call); row clamp for tails
  const int srow = tid >> 3;
  const int sj = tid & 7;
  const unsigned short* aptr[ACALLS];
#pragma unroll
  for (int p = 0; p < ACALLS; ++p) {
    int row = p * 32 + srow;
    int jj = sj ^ (row & 7);
    int mrow = m0 + row; if (mrow > cnt - 1) mrow = cnt - 1;
    int arow = SECOND ? (bas + mrow) : lst[mrow];
    aptr[p] = reinterpret_cast<const unsigned short*>(Ag) + (size_t)arow * K + jj * 8;
  }
  const unsigned short* bptr[BCALLS];
#pragma unroll
  for (int p = 0; p < BCALLS; ++p) {
    int row = p * 32 + srow;
    int jj = sj ^ (row & 7);
    bptr[p] = reinterpret_cast<const unsigned short*>(Wt) +
              ((size_t)e * NDIM + n0 + row) * K + jj * 8;
  }

  f32x4 acc[MF][NF] = {};

  for (int k0 = kz * KCH; k0 < (kz + 1) * KCH; k0 += BK) {
#pragma unroll
    for (int p = 0; p < ACALLS; ++p) GLD16(aptr[p] + k0, As + p * 4096 + (wave << 10));
#pragma unroll
    for (int p = 0; p < BCALLS; ++p) GLD16(bptr[p] + k0, Bs + p * 4096 + (wave << 10));
    __syncthreads();  // compiler drains vmcnt before barrier
#pragma unroll
    for (int s = 0; s < 2; ++s) {
      const int jA = s * 4 + (lane >> 4);
      short8 af[MF], bfr[NF];
#pragma unroll
      for (int mm = 0; mm < MF; ++mm) {
        int row = wrow + mm * 16 + (lane & 15);
        af[mm] = *reinterpret_cast<const short8*>(As + row * 128 + ((jA ^ (row & 7)) << 4));
      }
#pragma unroll
      for (int n = 0; n < NF; ++n) {
        int row = wcol + n * 16 + (lane & 15);
        bfr[n] = *reinterpret_cast<const short8*>(Bs + row * 128 + ((jA ^ (row & 7)) << 4));
      }
#pragma unroll
      for (int mm = 0; mm < MF; ++mm)
#pragma unroll
        for (int n = 0; n < NF; ++n)
          acc[mm][n] = __builtin_amdgcn_mfma_f32_16x16x32_bf16(af[mm], bfr[n], acc[mm][n], 0, 0, 0);
    }
    __syncthreads();  // reads done before next stage overwrites
  }

  // epilogue — C/D map: col = lane&15, row = (lane>>4)*4 + i
  const int colbase = n0 + wcol + (lane & 15);
  float bia[NF];
  if (!SECOND) {
#pragma unroll
    for (int n = 0; n < NF; ++n) bia[n] = bias[(size_t)e * NDIM + colbase + n * 16];
  }
#pragma unroll
  for (int mm = 0; mm < MF; ++mm) {
    const int rloc = wrow + mm * 16 + ((lane >> 4) << 2);
#pragma unroll
    for (int i = 0; i < 4; ++i) {
      const int r = m0 + rloc + i;
      if (r < cnt) {
        if (!SECOND) {
          __hip_bfloat16* hrow = hb + (size_t)(bas + r) * H + colbase;
#pragma unroll
          for (int n = 0; n < NF; ++n)
            hrow[n * 16] = __float2bfloat16(fmaxf(acc[mm][n][i] + bia[n], 0.f));
        } else {
          const int t = lst[r];
          const float sc = ws->rv[t];
          float* orow = outp + (size_t)t * D + colbase;
#pragma unroll
          for (int n = 0; n < NF; ++n)
            unsafeAtomicAdd(orow + n * 16, acc[mm][n][i] * sc);
        }
      }
    }
  }
}

}  // namespace

extern "C" void kernel_launch(void* const* d_in, const int* in_sizes, int n_in,
                              void* d_out, int out_size, void* d_ws, size_t ws_size,
                              hipStream_t stream) {
  const float* x  = (const float*)d_in[0];
  const float* Wg = (const float*)d_in[1];
  const float* bg = (const float*)d_in[2];
  const float* W1 = (const float*)d_in[3];
  const float* b1 = (const float*)d_in[4];
  const float* W2 = (const float*)d_in[5];
  const float* b2 = (const float*)d_in[6];
  float* out = (float*)d_out;
  WS* ws = (WS*)d_ws;
  char* wsb = (char*)d_ws;
  __hip_bfloat16* xb  = (__hip_bfloat16*)(wsb + XB_OFF);
  __hip_bfloat16* wt1 = (__hip_bfloat16*)(wsb + WT1_OFF);
  __hip_bfloat16* wt2 = (__hip_bfloat16*)(wsb + WT2_OFF);
  __hip_bfloat16* hbp = (__hip_bfloat16*)(wsb + HB_OFF);

  hipLaunchKernelGGL(route_k, dim3(T / 4), dim3(256), 0, stream,
                     x, Wg, bg, b2, xb, out, ws);
  hipLaunchKernelGGL(plan_k, dim3(1), dim3(1024), 0, stream, ws, out);
  hipLaunchKernelGGL(cvt_both, dim3(32, 8, 16), dim3(256), 0, stream, W1, W2, wt1, wt2);
  // flat grids: e = flat&7 -> XCD pinning
  hipLaunchKernelGGL((mgemm<D, 64, 128, 2, 2, 1, false>), dim3(E * (H / 128) * (T / 64)),
                     dim3(256), 0, stream, xb, wt1, b1, hbp, nullptr, ws);
  hipLaunchKernelGGL((mgemm<H, 64, 64, 2, 2, 2, true>), dim3(E * 2 * (D / 64) * (T / 64)),
                     dim3(256), 0, stream, hbp, wt2, b2, nullptr, out, ws);
}